// Round 13
// baseline (173.841 us; speedup 1.0000x reference)
//
#include <hip/hip_runtime.h>
#include <hip/hip_fp16.h>

#define N_NODES  50000
#define N_EDGES  300000
#define IN_FEATS 1433
#define HIDDEN   16
#define OUT_F    7
#define KPAD     1472   // zero-padded K extent
#define KSPLIT   768    // even blocks: k in [0,768) (12 iters); odd: [768,1472) (10+1 masked)
#define WROW     9      // dword stride per W row in LDS (odd -> 2 lanes/bank = free)

// ---------- Kernel 1: half-K partial GEMM. Block stages only its half of W1
// (27.6 KB LDS -> 5 blocks/CU = 20 waves/CU vs 12 before; in-flight bytes
// ~26KB/CU > 22KB Little's-law requirement for 6.3 TB/s). ----------
__global__ __launch_bounds__(256, 5) void k1_gemm_half(
    const float* __restrict__ F, const float* __restrict__ W1,
    __half* __restrict__ H0, __half* __restrict__ H1)
{
    __shared__ unsigned int Wl[KSPLIT * WROW];   // 27,648 B (max of both halves)
    const int tid    = threadIdx.x;
    const int halfId = blockIdx.x & 1;
    const int kbase  = halfId ? KSPLIT : 0;
    const int nrows  = halfId ? (KPAD - KSPLIT) : KSPLIT;   // 704 : 768

    // Stage this half's W rows as packed fp16 pairs (RNE), zero pad k>=1433
    for (int idx = tid; idx < nrows * 8; idx += 256) {
        int r = idx >> 3, c = idx & 7;
        int k = kbase + r;
        unsigned int u = 0u;
        if (k < IN_FEATS) {
            __half2 h2 = __floats2half2_rn(W1[k * 16 + 2 * c], W1[k * 16 + 2 * c + 1]);
            u = *reinterpret_cast<unsigned int*>(&h2);
        }
        Wl[r * WROW + c] = u;
    }
    __syncthreads();

    const int lane = tid & 63;
    const int ch = (blockIdx.x >> 1) * 4 + (tid >> 6);   // 0..12499, one chunk/wave
    const int r0 = ch * 4;
    const float* fp = F + (size_t)r0 * IN_FEATS + kbase;

    float v[64];                                    // acc[idx = r*16 + j]
    #pragma unroll
    for (int i = 0; i < 64; ++i) v[i] = 0.f;

    #define ITER_BODY(KL, M0, M1, M2, M3)                               \
        {                                                               \
            float wv[16];                                               \
            _Pragma("unroll")                                           \
            for (int c = 0; c < 8; ++c) {                               \
                unsigned int u = Wl[(KL) * WROW + c];                   \
                __half2 h2 = *reinterpret_cast<__half2*>(&u);           \
                float2 f = __half22float2(h2);                          \
                wv[2 * c]     = f.x;                                    \
                wv[2 * c + 1] = f.y;                                    \
            }                                                           \
            _Pragma("unroll")                                           \
            for (int j = 0; j < 16; ++j) {                              \
                v[j]      += (M0) * wv[j];                              \
                v[16 + j] += (M1) * wv[j];                              \
                v[32 + j] += (M2) * wv[j];                              \
                v[48 + j] += (M3) * wv[j];                              \
            }                                                           \
        }

    if (halfId == 0) {
        #pragma unroll 2
        for (int i = 0; i < 12; ++i) {              // k in [0,768): all clean
            const int kl = i * 64 + lane;
            const float f0 = fp[kl];
            const float f1 = fp[IN_FEATS + kl];
            const float f2 = fp[2 * IN_FEATS + kl];
            const float f3 = fp[3 * IN_FEATS + kl];
            ITER_BODY(kl, f0, f1, f2, f3);
        }
    } else {
        #pragma unroll 2
        for (int i = 0; i < 10; ++i) {              // k in [768,1408): clean
            const int kl = i * 64 + lane;
            const float f0 = fp[kl];
            const float f1 = fp[IN_FEATS + kl];
            const float f2 = fp[2 * IN_FEATS + kl];
            const float f3 = fp[3 * IN_FEATS + kl];
            ITER_BODY(kl, f0, f1, f2, f3);
        }
        {   // masked tail: global k = 1408 + lane, active k < 1433
            const int kl = 640 + lane;
            const bool m = (kbase + kl) < IN_FEATS;
            const float f0 = m ? fp[kl] : 0.f;
            const float f1 = m ? fp[IN_FEATS + kl] : 0.f;
            const float f2 = m ? fp[2 * IN_FEATS + kl] : 0.f;
            const float f3 = m ? fp[3 * IN_FEATS + kl] : 0.f;
            ITER_BODY(kl, f0, f1, f2, f3);          // W rows zero-padded
        }
    }
    #undef ITER_BODY

    // Halving butterfly: lane l ends with v[0] = half-K sum for idx = l
    #pragma unroll
    for (int d = 5; d >= 0; --d) {
        const int half = 1 << d;
        const bool hi = (lane >> d) & 1;
        #pragma unroll
        for (int t = 0; t < (1 << d); ++t) {
            float sent = hi ? v[t] : v[t + half];
            float recv = __shfl_xor(sent, half, 64);
            float keep = hi ? v[t + half] : v[t];
            v[t] = keep + recv;
        }
    }
    __half* Hout = halfId ? H1 : H0;
    Hout[(size_t)r0 * 16 + lane] = __float2half(v[0]);
}

// ---------- Kernel 1b: aggbuf = H0 + H1 + b1 (f32 math, fp16 store) ----------
__global__ __launch_bounds__(256) void k1b_combine(
    const __half2* __restrict__ H0, const __half2* __restrict__ H1,
    const float* __restrict__ b1, __half2* __restrict__ agg2)
{
    int t = blockIdx.x * 256 + threadIdx.x;
    if (t >= N_NODES * 8) return;
    int p = t & 7;
    float2 a = __half22float2(H0[t]);
    float2 b = __half22float2(H1[t]);
    agg2[t] = __floats2half2_rn(a.x + b.x + b1[2 * p],
                                a.y + b.y + b1[2 * p + 1]);
}

// ---------- Kernel 2: aggbuf[dst] += (H0+H1)[src], packed-fp16 atomics ----------
__global__ __launch_bounds__(256) void k2_scatter1(
    const int* __restrict__ src, const int* __restrict__ dst,
    const __half2* __restrict__ H0, const __half2* __restrict__ H1,
    __half2* __restrict__ agg2)
{
    int t = blockIdx.x * 256 + threadIdx.x;     // grid sized exactly N_EDGES*8
    int e = t >> 3, p = t & 7;
    int s = src[e], d = dst[e];
    __half2 val = __hadd2(H0[(size_t)s * 8 + p], H1[(size_t)s * 8 + p]);
    unsafeAtomicAdd(&agg2[(size_t)d * 8 + p], val);   // global_atomic_pk_add_f16
}

// ---------- Kernel 3: x = relu(aggbuf fp16); G = x @ W2; out = G + b2 ----------
__global__ __launch_bounds__(256) void k3_layer2(
    const __half2* __restrict__ agg2, const float* __restrict__ W2,
    const float* __restrict__ b2, float* __restrict__ G,
    float* __restrict__ out)
{
    int n = blockIdx.x * 256 + threadIdx.x;
    if (n >= N_NODES) return;
    float x[16];
    #pragma unroll
    for (int p = 0; p < 8; ++p) {
        float2 f = __half22float2(agg2[(size_t)n * 8 + p]);
        x[2 * p]     = f.x > 0.f ? f.x : 0.f;
        x[2 * p + 1] = f.y > 0.f ? f.y : 0.f;
    }
    #pragma unroll
    for (int j = 0; j < OUT_F; ++j) {
        float g = 0.f;
        #pragma unroll
        for (int k = 0; k < 16; ++k) g += x[k] * W2[k * OUT_F + j];
        G[(size_t)n * OUT_F + j] = g;
        out[(size_t)n * OUT_F + j] = g + b2[j];
    }
}

// ---------- Kernel 4: out[dst] += G[src], relaxed-scope f32 atomics ----------
__global__ __launch_bounds__(256) void k4_scatter2(
    const int* __restrict__ src, const int* __restrict__ dst,
    const float* __restrict__ G, float* __restrict__ out)
{
    int t = blockIdx.x * 256 + threadIdx.x;
    int e = t / OUT_F, j = t % OUT_F;
    if (e < N_EDGES) {
        unsafeAtomicAdd(&out[(size_t)dst[e] * OUT_F + j],
                        G[(size_t)src[e] * OUT_F + j]);
    }
}

extern "C" void kernel_launch(void* const* d_in, const int* in_sizes, int n_in,
                              void* d_out, int out_size, void* d_ws, size_t ws_size,
                              hipStream_t stream)
{
    const float* F   = (const float*)d_in[0];
    const int*   src = (const int*)d_in[1];
    const int*   dst = (const int*)d_in[2];
    const float* W1  = (const float*)d_in[3];
    const float* b1  = (const float*)d_in[4];
    const float* W2  = (const float*)d_in[5];
    const float* b2  = (const float*)d_in[6];
    float* out = (float*)d_out;

    __half* H0     = (__half*)d_ws;                         // 800,000 fp16
    __half* H1     = H0 + (size_t)N_NODES * HIDDEN;         // 800,000 fp16
    __half* aggbuf = H1 + (size_t)N_NODES * HIDDEN;         // 800,000 fp16
    float*  G      = (float*)H0;                            // alias: H0 dead after k2

    // 6250 blocks: even = k-half 0, odd = k-half 1; 4 waves/block, 1 chunk/wave
    k1_gemm_half<<<6250, 256, 0, stream>>>(F, W1, H0, H1);
    k1b_combine<<<(N_NODES * 8 + 255) / 256, 256, 0, stream>>>(
        (const __half2*)H0, (const __half2*)H1, b1, (__half2*)aggbuf);
    k2_scatter1<<<(N_EDGES * 8) / 256, 256, 0, stream>>>(src, dst,
        (const __half2*)H0, (const __half2*)H1, (__half2*)aggbuf);
    k3_layer2<<<(N_NODES + 255) / 256, 256, 0, stream>>>((const __half2*)aggbuf,
        W2, b2, G, out);
    k4_scatter2<<<(N_EDGES * OUT_F + 255) / 256, 256, 0, stream>>>(src, dst, G, out);
}

// Round 14
// 122.433 us; speedup vs baseline: 1.4199x; 1.4199x over previous
//
#include <hip/hip_runtime.h>
#include <hip/hip_fp16.h>

#define N_NODES  50000
#define N_EDGES  300000
#define IN_FEATS 1433
#define HIDDEN   16
#define OUT_F    7
#define NSTEP    45            // K-steps of 32: 45*32 = 1440 >= 1433
#define NCHUNK   3125          // 50000 / 16 row-tiles

typedef __attribute__((ext_vector_type(8))) _Float16 f16x8;
typedef __attribute__((ext_vector_type(4))) float    f32x4;

// ---------- k0: pack W1 (1433x16 f32) into MFMA B-fragment order ----------
// Wb[s*512 + l*8 + i] = W1[k][n], k = s*32 + (l>>4)*8 + i, n = l&15; 0 if k>=1433.
__global__ __launch_bounds__(256) void k0_pack(const float* __restrict__ W1,
                                               __half* __restrict__ Wb)
{
    int t = blockIdx.x * 256 + threadIdx.x;          // 45*512 = 23040 = 90*256 exact
    int s = t >> 9, rem = t & 511, l = rem >> 3, i = rem & 7;
    int k = s * 32 + ((l >> 4) << 3) + i, n = l & 15;
    float v = (k < IN_FEATS) ? W1[k * 16 + n] : 0.f;
    Wb[t] = __float2half(v);
}

// ---------- k1: H = F @ W1 via MFMA; aggbuf = H + b1 ----------
// One wave per 16-row tile. Per K-step: 8 scalar F-loads (odd pitch forbids
// vectors), cvt->f16 A-frag, dwordx4 B-frag from L2-resident Wb, 1 MFMA.
// No LDS, no syncthreads -> loads pipeline across steps (unroll 4).
__global__ __launch_bounds__(256) void k1_mfma(
    const float* __restrict__ F, const __half* __restrict__ Wb,
    const float* __restrict__ b1, __half* __restrict__ H,
    __half* __restrict__ aggbuf)
{
    const int tid = threadIdx.x;
    const int wid = blockIdx.x * 4 + (tid >> 6);
    if (wid >= NCHUNK) return;
    const int lane = tid & 63;
    const int m  = lane & 15;         // A-row within tile; also D-col (hidden j)
    const int kg = lane >> 4;         // 0..3
    const int r0 = wid * 16;
    const float* fa = F + (size_t)(r0 + m) * IN_FEATS + kg * 8;
    const f16x8* Wf = (const f16x8*)Wb;

    f32x4 acc = {0.f, 0.f, 0.f, 0.f};

    #pragma unroll 4
    for (int s = 0; s < NSTEP - 1; ++s) {            // k < 1432: all in-bounds
        const float* p = fa + s * 32;
        f16x8 av;
        av[0] = (_Float16)p[0]; av[1] = (_Float16)p[1];
        av[2] = (_Float16)p[2]; av[3] = (_Float16)p[3];
        av[4] = (_Float16)p[4]; av[5] = (_Float16)p[5];
        av[6] = (_Float16)p[6]; av[7] = (_Float16)p[7];
        f16x8 bv = Wf[s * 64 + lane];
        acc = __builtin_amdgcn_mfma_f32_16x16x32_f16(av, bv, acc, 0, 0, 0);
    }
    {   // step 44: k = 1408 + kg*8 + i; kg==3 & i>0 -> k>1432: mask loads
        // (values would multiply zero B rows anyway; mask is for OOB safety)
        const float* p = fa + 44 * 32;
        const bool hi = (kg == 3);
        f16x8 av;
        av[0] = (_Float16)p[0];
        av[1] = (_Float16)(hi ? 0.f : p[1]);
        av[2] = (_Float16)(hi ? 0.f : p[2]);
        av[3] = (_Float16)(hi ? 0.f : p[3]);
        av[4] = (_Float16)(hi ? 0.f : p[4]);
        av[5] = (_Float16)(hi ? 0.f : p[5]);
        av[6] = (_Float16)(hi ? 0.f : p[6]);
        av[7] = (_Float16)(hi ? 0.f : p[7]);
        f16x8 bv = Wf[44 * 64 + lane];
        acc = __builtin_amdgcn_mfma_f32_16x16x32_f16(av, bv, acc, 0, 0, 0);
    }

    // D layout: col = lane&15 (= m), rows = r0 + kg*4 + i
    const float bj = b1[m];
    #pragma unroll
    for (int i = 0; i < 4; ++i) {
        const int row = r0 + kg * 4 + i;
        const float v = acc[i];
        H[(size_t)row * 16 + m]      = __float2half(v);
        aggbuf[(size_t)row * 16 + m] = __float2half(v + bj);
    }
}

// ---------- k2: aggbuf[dst] += H[src], packed-fp16 atomics ----------
__global__ __launch_bounds__(256) void k2_scatter1(
    const int* __restrict__ src, const int* __restrict__ dst,
    const __half2* __restrict__ H2, __half2* __restrict__ agg2)
{
    int t = blockIdx.x * 256 + threadIdx.x;     // grid exactly N_EDGES*8
    int e = t >> 3, p = t & 7;
    int s = src[e], d = dst[e];
    unsafeAtomicAdd(&agg2[(size_t)d * 8 + p], H2[(size_t)s * 8 + p]);
}

// ---------- k3: x = relu(aggbuf); G = x@W2; Gh = G (fp16, 8-pad); oacc = G+b2 ----------
__global__ __launch_bounds__(256) void k3_layer2(
    const __half2* __restrict__ agg2, const float* __restrict__ W2,
    const float* __restrict__ b2, __half* __restrict__ Gh,
    __half* __restrict__ oacc)
{
    int n = blockIdx.x * 256 + threadIdx.x;
    if (n >= N_NODES) return;
    float x[16];
    #pragma unroll
    for (int p = 0; p < 8; ++p) {
        float2 f = __half22float2(agg2[(size_t)n * 8 + p]);
        x[2 * p]     = f.x > 0.f ? f.x : 0.f;
        x[2 * p + 1] = f.y > 0.f ? f.y : 0.f;
    }
    float g[8], o[8];
    #pragma unroll
    for (int j = 0; j < 7; ++j) {
        float s = 0.f;
        #pragma unroll
        for (int k = 0; k < 16; ++k) s += x[k] * W2[k * OUT_F + j];
        g[j] = s;
        o[j] = s + b2[j];
    }
    g[7] = 0.f; o[7] = 0.f;

    union U { uint4 u; __half2 h[4]; };
    U gu, ou;
    #pragma unroll
    for (int p = 0; p < 4; ++p) {
        gu.h[p] = __floats2half2_rn(g[2 * p], g[2 * p + 1]);
        ou.h[p] = __floats2half2_rn(o[2 * p], o[2 * p + 1]);
    }
    *(uint4*)(Gh   + (size_t)n * 8) = gu.u;
    *(uint4*)(oacc + (size_t)n * 8) = ou.u;
}

// ---------- k4: oacc[dst] += Gh[src], packed-fp16 atomics (4/edge) ----------
__global__ __launch_bounds__(256) void k4_scatter2(
    const int* __restrict__ src, const int* __restrict__ dst,
    const __half2* __restrict__ Gh2, __half2* __restrict__ oacc2)
{
    int t = blockIdx.x * 256 + threadIdx.x;
    if (t >= N_EDGES * 4) return;
    int e = t >> 2, p = t & 3;
    unsafeAtomicAdd(&oacc2[(size_t)dst[e] * 4 + p], Gh2[(size_t)src[e] * 4 + p]);
}

// ---------- k5: out (f32, 7-wide) = oacc (fp16, 8-pad) ----------
__global__ __launch_bounds__(256) void k5_out(
    const __half* __restrict__ oacc, float* __restrict__ out)
{
    int t = blockIdx.x * 256 + threadIdx.x;
    if (t >= N_NODES * OUT_F) return;
    int n = t / 7, j = t - n * 7;
    out[t] = __half2float(oacc[(size_t)n * 8 + j]);
}

extern "C" void kernel_launch(void* const* d_in, const int* in_sizes, int n_in,
                              void* d_out, int out_size, void* d_ws, size_t ws_size,
                              hipStream_t stream)
{
    const float* F   = (const float*)d_in[0];
    const int*   src = (const int*)d_in[1];
    const int*   dst = (const int*)d_in[2];
    const float* W1  = (const float*)d_in[3];
    const float* b1  = (const float*)d_in[4];
    const float* W2  = (const float*)d_in[5];
    const float* b2  = (const float*)d_in[6];
    float* out = (float*)d_out;

    __half* H    = (__half*)d_ws;                       // 800,000 fp16
    __half* agg  = H + (size_t)N_NODES * HIDDEN;        // 800,000 fp16
    __half* Wb   = agg + (size_t)N_NODES * HIDDEN;      // 23,040 fp16 (46 KB)
    __half* Gh   = Wb + NSTEP * 512;                    // 400,000 fp16
    __half* oacc = Gh + (size_t)N_NODES * 8;            // 400,000 fp16

    k0_pack<<<(NSTEP * 512) / 256, 256, 0, stream>>>(W1, Wb);
    k1_mfma<<<(NCHUNK + 3) / 4, 256, 0, stream>>>(F, Wb, b1, H, agg);
    k2_scatter1<<<(N_EDGES * 8) / 256, 256, 0, stream>>>(src, dst,
        (const __half2*)H, (__half2*)agg);
    k3_layer2<<<(N_NODES + 255) / 256, 256, 0, stream>>>((const __half2*)agg,
        W2, b2, Gh, oacc);
    k4_scatter2<<<(N_EDGES * 4 + 255) / 256, 256, 0, stream>>>(src, dst,
        (const __half2*)Gh, (__half2*)oacc);
    k5_out<<<(N_NODES * OUT_F + 255) / 256, 256, 0, stream>>>(oacc, out);
}